// Round 14
// baseline (219.183 us; speedup 1.0000x reference)
//
#include <hip/hip_runtime.h>
#include <math.h>

// Causal SDPA, B=4 H=8 S=2048 D=64, scale = 1/sqrt(512)  (HIDDEN_SIZE=512).
// d_out (fp32): [B,H,S,D] output O followed by [B,H,S,S] attn probs P.
// Inputs fp32. mask input ignored (statically causal, triu k=1).
//
// R14 = R13 (207.8us) with __launch_bounds__(256,4): cap VGPR at 128 ->
// 4 blocks/CU (LDS 27.6KB x4 = 110KB < 160KB) -> 2x TLP for latency hiding.

#define S_LEN 2048
#define SCALE 0.04419417382415922f  // 1/sqrt(512)

typedef __attribute__((ext_vector_type(8))) short bf16x8;
typedef __attribute__((ext_vector_type(4))) short bf16x4;
typedef __attribute__((ext_vector_type(4))) float f32x4;

__device__ __forceinline__ short f2bf(float f) {
  unsigned u = __builtin_bit_cast(unsigned, f);
  u = (u + 0x7FFFu + ((u >> 16) & 1u)) >> 16;
  return (short)u;
}

__device__ __forceinline__ bf16x8 pack8(float4 a, float4 b) {
  bf16x8 t;
  t[0] = f2bf(a.x); t[1] = f2bf(a.y); t[2] = f2bf(a.z); t[3] = f2bf(a.w);
  t[4] = f2bf(b.x); t[5] = f2bf(b.y); t[6] = f2bf(b.z); t[7] = f2bf(b.w);
  return t;
}

__device__ __forceinline__ void nt_store4(float* p, float x, float y, float z2, float w2) {
  f32x4 v; v[0] = x; v[1] = y; v[2] = z2; v[3] = w2;
  __builtin_nontemporal_store(v, (f32x4*)p);
}

// LDS rows padded to 72 halfs (144 B): 16B-aligned rows, bank-group rotation.
__global__ __launch_bounds__(256, 4)
void sdpa_kernel(const float* Q, const float* K, const float* V,
                 float* outO, float* outP)
{
  __shared__ __align__(16) short ldsK[64][72];      // K tile   [k][d]
  __shared__ __align__(16) short ldsV[64][72];      // V^T tile [d][k]
  __shared__ __align__(16) short ldsP[4][16][72];   // per-wave P tile [q][k]

  const int tid  = threadIdx.x;
  const int lane = tid & 63;
  const int w    = tid >> 6;
  const int lrow = lane & 15;   // q-row lane index (S^T cols / O d-cols)
  const int lgrp = lane >> 4;

  // heavy q-tiles first: no load-imbalance tail
  const int qt = 31 - (blockIdx.x >> 5);
  const int bh = blockIdx.x & 31;
  const int q0 = qt << 6;
  const int qrow = q0 + (w << 4) + lrow;   // this lane's q row

  // staging map: thread covers tile row sr, 16 floats from col sc
  const int sr = tid & 63;
  const int sc = (tid >> 6) << 4;

  const size_t pOutBase = (size_t)bh * S_LEN * S_LEN;
  const int kz = (qt + 1) << 6;            // first strictly-masked col

  // Q fragment (B operand of S^T = K*Q^T): lane holds Q[qrow][ks*32+lgrp*8..+7]
  bf16x8 qf[2];
  {
    const float* qb = Q + ((size_t)(bh * S_LEN + qrow)) * 64;
#pragma unroll
    for (int ks = 0; ks < 2; ++ks) {
      const float* p = qb + ks * 32 + lgrp * 8;
      qf[ks] = pack8(*(const float4*)p, *(const float4*)(p + 4));
    }
  }

  float m_run = -INFINITY;
  float l_run = 0.f;

  // ===== pass 1: exact row max + denominator; zero-fill interleaved =====
  for (int kt = 0; kt <= qt; ++kt) {
    __syncthreads();
    {
      const float* src = K + ((size_t)(bh * S_LEN + (kt << 6) + sr)) * 64 + sc;
      float4 a0 = ((const float4*)src)[0];
      float4 a1 = ((const float4*)src)[1];
      float4 a2 = ((const float4*)src)[2];
      float4 a3 = ((const float4*)src)[3];
      *(bf16x8*)&ldsK[sr][sc]     = pack8(a0, a1);
      *(bf16x8*)&ldsK[sr][sc + 8] = pack8(a2, a3);
    }

    // ---- interleaved zero stores: slice kt of the masked region ----
    if (kz < S_LEN) {
      const int r0 = (kt * 64) / (qt + 1);
      const int r1 = ((kt + 1) * 64) / (qt + 1);
      for (int r = r0; r < r1; ++r) {
        const size_t base = pOutBase + (size_t)(q0 + r) * S_LEN;
        for (int c = kz + (tid << 2); c < S_LEN; c += 256 * 4) {
          nt_store4(outP + base + c, 0.f, 0.f, 0.f, 0.f);
        }
      }
    }
    __syncthreads();

    f32x4 acc[4];
#pragma unroll
    for (int nt = 0; nt < 4; ++nt) {
      f32x4 a = {0.f, 0.f, 0.f, 0.f};
#pragma unroll
      for (int ks = 0; ks < 2; ++ks) {
        bf16x8 kfrag = *(const bf16x8*)&ldsK[nt * 16 + lrow][ks * 32 + lgrp * 8];
        a = __builtin_amdgcn_mfma_f32_16x16x32_bf16(kfrag, qf[ks], a, 0, 0, 0);
      }
      acc[nt] = a;
    }

    // scale (+ mask only on diagonal tile); lane's 16 regs all belong to qrow
    if (kt == qt) {
#pragma unroll
      for (int nt = 0; nt < 4; ++nt)
#pragma unroll
        for (int rg = 0; rg < 4; ++rg) {
          const int col = (kt << 6) + nt * 16 + (lgrp << 2) + rg;
          acc[nt][rg] = (col > qrow) ? -INFINITY : acc[nt][rg] * SCALE;
        }
    } else {
#pragma unroll
      for (int nt = 0; nt < 4; ++nt)
#pragma unroll
        for (int rg = 0; rg < 4; ++rg) acc[nt][rg] *= SCALE;
    }

    float tm = -INFINITY;
#pragma unroll
    for (int nt = 0; nt < 4; ++nt)
#pragma unroll
      for (int rg = 0; rg < 4; ++rg) tm = fmaxf(tm, acc[nt][rg]);
    tm = fmaxf(tm, __shfl_xor(tm, 16));
    tm = fmaxf(tm, __shfl_xor(tm, 32));
    const float nm = fmaxf(m_run, tm);

    float ps = 0.f;
#pragma unroll
    for (int nt = 0; nt < 4; ++nt)
#pragma unroll
      for (int rg = 0; rg < 4; ++rg) ps += __expf(acc[nt][rg] - nm);
    ps += __shfl_xor(ps, 16);
    ps += __shfl_xor(ps, 32);

    l_run = l_run * __expf(m_run - nm) + ps;
    m_run = nm;
  }

  const float inv_l = 1.f / l_run;

  f32x4 oacc[4];
#pragma unroll
  for (int nt = 0; nt < 4; ++nt) oacc[nt] = (f32x4){0.f, 0.f, 0.f, 0.f};

  const size_t pbase = pOutBase + (size_t)qrow * S_LEN;

  // ================= pass 2: probs, attn store, PV =================
  for (int kt = 0; kt <= qt; ++kt) {
    __syncthreads();
    {
      const float* srcK = K + ((size_t)(bh * S_LEN + (kt << 6) + sr)) * 64 + sc;
      float4 a0 = ((const float4*)srcK)[0];
      float4 a1 = ((const float4*)srcK)[1];
      float4 a2 = ((const float4*)srcK)[2];
      float4 a3 = ((const float4*)srcK)[3];
      *(bf16x8*)&ldsK[sr][sc]     = pack8(a0, a1);
      *(bf16x8*)&ldsK[sr][sc + 8] = pack8(a2, a3);

      const float* srcV = V + ((size_t)(bh * S_LEN + (kt << 6) + sr)) * 64 + sc;
      float4 b0 = ((const float4*)srcV)[0];
      float4 b1 = ((const float4*)srcV)[1];
      float4 b2 = ((const float4*)srcV)[2];
      float4 b3 = ((const float4*)srcV)[3];
      const float vv[16] = {b0.x, b0.y, b0.z, b0.w, b1.x, b1.y, b1.z, b1.w,
                            b2.x, b2.y, b2.z, b2.w, b3.x, b3.y, b3.z, b3.w};
#pragma unroll
      for (int j = 0; j < 16; ++j) ldsV[sc + j][sr] = f2bf(vv[j]);  // transpose
    }
    __syncthreads();

    f32x4 acc[4];
#pragma unroll
    for (int nt = 0; nt < 4; ++nt) {
      f32x4 a = {0.f, 0.f, 0.f, 0.f};
#pragma unroll
      for (int ks = 0; ks < 2; ++ks) {
        bf16x8 kfrag = *(const bf16x8*)&ldsK[nt * 16 + lrow][ks * 32 + lgrp * 8];
        a = __builtin_amdgcn_mfma_f32_16x16x32_bf16(kfrag, qf[ks], a, 0, 0, 0);
      }
      acc[nt] = a;
    }

    if (kt == qt) {
#pragma unroll
      for (int nt = 0; nt < 4; ++nt)
#pragma unroll
        for (int rg = 0; rg < 4; ++rg) {
          const int col = (kt << 6) + nt * 16 + (lgrp << 2) + rg;
          acc[nt][rg] = (col > qrow) ? -INFINITY : acc[nt][rg] * SCALE;
        }
    } else {
#pragma unroll
      for (int nt = 0; nt < 4; ++nt)
#pragma unroll
        for (int rg = 0; rg < 4; ++rg) acc[nt][rg] *= SCALE;
    }

    // probabilities: NT float4 global store + b64 LDS store per nt
#pragma unroll
    for (int nt = 0; nt < 4; ++nt) {
      float p0 = __expf(acc[nt][0] - m_run) * inv_l;
      float p1 = __expf(acc[nt][1] - m_run) * inv_l;
      float p2 = __expf(acc[nt][2] - m_run) * inv_l;
      float p3 = __expf(acc[nt][3] - m_run) * inv_l;
      nt_store4(outP + pbase + (kt << 6) + nt * 16 + (lgrp << 2), p0, p1, p2, p3);
      bf16x4 pb;
      pb[0] = f2bf(p0); pb[1] = f2bf(p1);
      pb[2] = f2bf(p2); pb[3] = f2bf(p3);
      *(bf16x4*)&ldsP[w][lrow][nt * 16 + (lgrp << 2)] = pb;
    }

    // PV: A = own-wave P tile (16q x 64k), B = V^T tile (same-wave LDS
    // write->read; ldsP[w] is wave-private, ordered by lgkmcnt).
#pragma unroll
    for (int nt = 0; nt < 4; ++nt) {
#pragma unroll
      for (int ks = 0; ks < 2; ++ks) {
        bf16x8 pa = *(const bf16x8*)&ldsP[w][lrow][ks * 32 + lgrp * 8];
        bf16x8 vb = *(const bf16x8*)&ldsV[nt * 16 + lrow][ks * 32 + lgrp * 8];
        oacc[nt] = __builtin_amdgcn_mfma_f32_16x16x32_bf16(pa, vb, oacc[nt], 0, 0, 0);
      }
    }
  }

  // ---- write O (fp32): O row = q0+16w+4*lgrp+rg, col d = nt*16+lrow ----
#pragma unroll
  for (int nt = 0; nt < 4; ++nt) {
#pragma unroll
    for (int rg = 0; rg < 4; ++rg) {
      const int rl = (lgrp << 2) + rg;
      const int d  = nt * 16 + lrow;
      __builtin_nontemporal_store(
          oacc[nt][rg],
          outO + ((size_t)(bh * S_LEN + q0 + (w << 4) + rl)) * 64 + d);
    }
  }
}

extern "C" void kernel_launch(void* const* d_in, const int* in_sizes, int n_in,
                              void* d_out, int out_size, void* d_ws, size_t ws_size,
                              hipStream_t stream) {
  const float* Q = (const float*)d_in[0];
  const float* K = (const float*)d_in[1];
  const float* V = (const float*)d_in[2];
  // d_in[3] (mask) is statically causal -> not read.
  float* outO = (float*)d_out;
  float* outP = outO + (size_t)32 * S_LEN * 64;  // after [B,H,S,D] output
  sdpa_kernel<<<dim3(32 * 32), dim3(256), 0, stream>>>(Q, K, V, outO, outP);
}

// Round 15
// 198.021 us; speedup vs baseline: 1.1069x; 1.1069x over previous
//
#include <hip/hip_runtime.h>
#include <math.h>

// Causal SDPA, B=4 H=8 S=2048 D=64, scale = 1/sqrt(512)  (HIDDEN_SIZE=512).
// d_out (fp32): [B,H,S,D] output O followed by [B,H,S,S] attn probs P.
// Inputs fp32. mask input ignored (statically causal, triu k=1).
//
// R15 = R13 (207.8us, best) with ONE change: K/V staged from bf16
// workspace copies (transcoded once) -> staging re-read bytes halved
// (810 -> 405 MB). Same 256-thread/4-wave structure, zero-interleave,
// NT stores, launch_bounds(256,2).

#define S_LEN 2048
#define SCALE 0.04419417382415922f  // 1/sqrt(512)
#define NELEM 4194304               // 4*8*2048*64 per tensor

typedef __attribute__((ext_vector_type(8))) short bf16x8;
typedef __attribute__((ext_vector_type(4))) short bf16x4;
typedef __attribute__((ext_vector_type(4))) float f32x4;

__device__ __forceinline__ short f2bf(float f) {
  unsigned u = __builtin_bit_cast(unsigned, f);
  u = (u + 0x7FFFu + ((u >> 16) & 1u)) >> 16;
  return (short)u;
}

__device__ __forceinline__ bf16x8 pack8(float4 a, float4 b) {
  bf16x8 t;
  t[0] = f2bf(a.x); t[1] = f2bf(a.y); t[2] = f2bf(a.z); t[3] = f2bf(a.w);
  t[4] = f2bf(b.x); t[5] = f2bf(b.y); t[6] = f2bf(b.z); t[7] = f2bf(b.w);
  return t;
}

__device__ __forceinline__ void nt_store4(float* p, float x, float y, float z2, float w2) {
  f32x4 v; v[0] = x; v[1] = y; v[2] = z2; v[3] = w2;
  __builtin_nontemporal_store(v, (f32x4*)p);
}

// ---- prep: fp32 -> bf16 row-major transcode of K and V into workspace ----
__global__ __launch_bounds__(256)
void transcode_kernel(const float* K, const float* V, short* Kw, short* Vw) {
  const size_t i = ((size_t)blockIdx.x * 256 + threadIdx.x) * 8;
  if (i < NELEM) {
    const float4* k4 = (const float4*)(K + i);
    *(bf16x8*)(Kw + i) = pack8(k4[0], k4[1]);
    const float4* v4 = (const float4*)(V + i);
    *(bf16x8*)(Vw + i) = pack8(v4[0], v4[1]);
  }
}

// LDS rows padded to 72 halfs (144 B): 16B-aligned rows, bank-group rotation.
template <bool SRC16>
__global__ __launch_bounds__(256, 2)
void sdpa_kernel(const float* Q, const void* Ksrc, const void* Vsrc,
                 float* outO, float* outP)
{
  __shared__ __align__(16) short ldsK[64][72];      // K tile   [k][d]
  __shared__ __align__(16) short ldsV[64][72];      // V^T tile [d][k]
  __shared__ __align__(16) short ldsP[4][16][72];   // per-wave P tile [q][k]

  const int tid  = threadIdx.x;
  const int lane = tid & 63;
  const int w    = tid >> 6;
  const int lrow = lane & 15;   // q-row lane index (S^T cols / O d-cols)
  const int lgrp = lane >> 4;

  // heavy q-tiles first: no load-imbalance tail
  const int qt = 31 - (blockIdx.x >> 5);
  const int bh = blockIdx.x & 31;
  const int q0 = qt << 6;
  const int qrow = q0 + (w << 4) + lrow;   // this lane's q row

  // staging map: thread covers tile row sr, 16 elems from col sc
  const int sr = tid & 63;
  const int sc = (tid >> 6) << 4;

  const size_t pOutBase = (size_t)bh * S_LEN * S_LEN;
  const int kz = (qt + 1) << 6;            // first strictly-masked col

  // staging macros: bf16 workspace path (SRC16) or fp32 fallback
#define STAGEK(kt) {                                                          \
    if (SRC16) {                                                              \
      const short* s_ = (const short*)Ksrc +                                  \
          ((size_t)(bh * S_LEN + ((kt) << 6) + sr)) * 64 + sc;                \
      *(bf16x8*)&ldsK[sr][sc]     = ((const bf16x8*)s_)[0];                   \
      *(bf16x8*)&ldsK[sr][sc + 8] = ((const bf16x8*)s_)[1];                   \
    } else {                                                                  \
      const float* s_ = (const float*)Ksrc +                                  \
          ((size_t)(bh * S_LEN + ((kt) << 6) + sr)) * 64 + sc;                \
      *(bf16x8*)&ldsK[sr][sc]     = pack8(((const float4*)s_)[0],             \
                                          ((const float4*)s_)[1]);            \
      *(bf16x8*)&ldsK[sr][sc + 8] = pack8(((const float4*)s_)[2],             \
                                          ((const float4*)s_)[3]);            \
    } }

#define STAGEV(kt) {                                                          \
    if (SRC16) {                                                              \
      const short* s_ = (const short*)Vsrc +                                  \
          ((size_t)(bh * S_LEN + ((kt) << 6) + sr)) * 64 + sc;                \
      bf16x8 v0_ = ((const bf16x8*)s_)[0];                                    \
      bf16x8 v1_ = ((const bf16x8*)s_)[1];                                    \
      _Pragma("unroll")                                                       \
      for (int j_ = 0; j_ < 8; ++j_) ldsV[sc + j_][sr] = v0_[j_];             \
      _Pragma("unroll")                                                       \
      for (int j_ = 0; j_ < 8; ++j_) ldsV[sc + 8 + j_][sr] = v1_[j_];         \
    } else {                                                                  \
      const float* s_ = (const float*)Vsrc +                                  \
          ((size_t)(bh * S_LEN + ((kt) << 6) + sr)) * 64 + sc;                \
      float4 b0_ = ((const float4*)s_)[0];                                    \
      float4 b1_ = ((const float4*)s_)[1];                                    \
      float4 b2_ = ((const float4*)s_)[2];                                    \
      float4 b3_ = ((const float4*)s_)[3];                                    \
      const float vv_[16] = {b0_.x, b0_.y, b0_.z, b0_.w, b1_.x, b1_.y, b1_.z, \
                             b1_.w, b2_.x, b2_.y, b2_.z, b2_.w, b3_.x, b3_.y, \
                             b3_.z, b3_.w};                                   \
      _Pragma("unroll")                                                       \
      for (int j_ = 0; j_ < 16; ++j_) ldsV[sc + j_][sr] = f2bf(vv_[j_]);      \
    } }

  // Q fragment (B operand of S^T = K*Q^T): lane holds Q[qrow][ks*32+lgrp*8..+7]
  bf16x8 qf[2];
  {
    const float* qb = Q + ((size_t)(bh * S_LEN + qrow)) * 64;
#pragma unroll
    for (int ks = 0; ks < 2; ++ks) {
      const float* p = qb + ks * 32 + lgrp * 8;
      qf[ks] = pack8(*(const float4*)p, *(const float4*)(p + 4));
    }
  }

  float m_run = -INFINITY;
  float l_run = 0.f;

  // ===== pass 1: exact row max + denominator; zero-fill interleaved =====
  for (int kt = 0; kt <= qt; ++kt) {
    __syncthreads();
    STAGEK(kt)

    // ---- interleaved zero stores: slice kt of the masked region ----
    if (kz < S_LEN) {
      const int r0 = (kt * 64) / (qt + 1);
      const int r1 = ((kt + 1) * 64) / (qt + 1);
      for (int r = r0; r < r1; ++r) {
        const size_t base = pOutBase + (size_t)(q0 + r) * S_LEN;
        for (int c = kz + (tid << 2); c < S_LEN; c += 256 * 4) {
          nt_store4(outP + base + c, 0.f, 0.f, 0.f, 0.f);
        }
      }
    }
    __syncthreads();

    f32x4 acc[4];
#pragma unroll
    for (int nt = 0; nt < 4; ++nt) {
      f32x4 a = {0.f, 0.f, 0.f, 0.f};
#pragma unroll
      for (int ks = 0; ks < 2; ++ks) {
        bf16x8 kfrag = *(const bf16x8*)&ldsK[nt * 16 + lrow][ks * 32 + lgrp * 8];
        a = __builtin_amdgcn_mfma_f32_16x16x32_bf16(kfrag, qf[ks], a, 0, 0, 0);
      }
      acc[nt] = a;
    }

    // scale (+ mask only on diagonal tile); lane's 16 regs all belong to qrow
    if (kt == qt) {
#pragma unroll
      for (int nt = 0; nt < 4; ++nt)
#pragma unroll
        for (int rg = 0; rg < 4; ++rg) {
          const int col = (kt << 6) + nt * 16 + (lgrp << 2) + rg;
          acc[nt][rg] = (col > qrow) ? -INFINITY : acc[nt][rg] * SCALE;
        }
    } else {
#pragma unroll
      for (int nt = 0; nt < 4; ++nt)
#pragma unroll
        for (int rg = 0; rg < 4; ++rg) acc[nt][rg] *= SCALE;
    }

    float tm = -INFINITY;
#pragma unroll
    for (int nt = 0; nt < 4; ++nt)
#pragma unroll
      for (int rg = 0; rg < 4; ++rg) tm = fmaxf(tm, acc[nt][rg]);
    tm = fmaxf(tm, __shfl_xor(tm, 16));
    tm = fmaxf(tm, __shfl_xor(tm, 32));
    const float nm = fmaxf(m_run, tm);

    float ps = 0.f;
#pragma unroll
    for (int nt = 0; nt < 4; ++nt)
#pragma unroll
      for (int rg = 0; rg < 4; ++rg) ps += __expf(acc[nt][rg] - nm);
    ps += __shfl_xor(ps, 16);
    ps += __shfl_xor(ps, 32);

    l_run = l_run * __expf(m_run - nm) + ps;
    m_run = nm;
  }

  const float inv_l = 1.f / l_run;

  f32x4 oacc[4];
#pragma unroll
  for (int nt = 0; nt < 4; ++nt) oacc[nt] = (f32x4){0.f, 0.f, 0.f, 0.f};

  const size_t pbase = pOutBase + (size_t)qrow * S_LEN;

  // ================= pass 2: probs, attn store, PV =================
  for (int kt = 0; kt <= qt; ++kt) {
    __syncthreads();
    STAGEK(kt)
    STAGEV(kt)
    __syncthreads();

    f32x4 acc[4];
#pragma unroll
    for (int nt = 0; nt < 4; ++nt) {
      f32x4 a = {0.f, 0.f, 0.f, 0.f};
#pragma unroll
      for (int ks = 0; ks < 2; ++ks) {
        bf16x8 kfrag = *(const bf16x8*)&ldsK[nt * 16 + lrow][ks * 32 + lgrp * 8];
        a = __builtin_amdgcn_mfma_f32_16x16x32_bf16(kfrag, qf[ks], a, 0, 0, 0);
      }
      acc[nt] = a;
    }

    if (kt == qt) {
#pragma unroll
      for (int nt = 0; nt < 4; ++nt)
#pragma unroll
        for (int rg = 0; rg < 4; ++rg) {
          const int col = (kt << 6) + nt * 16 + (lgrp << 2) + rg;
          acc[nt][rg] = (col > qrow) ? -INFINITY : acc[nt][rg] * SCALE;
        }
    } else {
#pragma unroll
      for (int nt = 0; nt < 4; ++nt)
#pragma unroll
        for (int rg = 0; rg < 4; ++rg) acc[nt][rg] *= SCALE;
    }

    // probabilities: NT float4 global store + b64 LDS store per nt
#pragma unroll
    for (int nt = 0; nt < 4; ++nt) {
      float p0 = __expf(acc[nt][0] - m_run) * inv_l;
      float p1 = __expf(acc[nt][1] - m_run) * inv_l;
      float p2 = __expf(acc[nt][2] - m_run) * inv_l;
      float p3 = __expf(acc[nt][3] - m_run) * inv_l;
      nt_store4(outP + pbase + (kt << 6) + nt * 16 + (lgrp << 2), p0, p1, p2, p3);
      bf16x4 pb;
      pb[0] = f2bf(p0); pb[1] = f2bf(p1);
      pb[2] = f2bf(p2); pb[3] = f2bf(p3);
      *(bf16x4*)&ldsP[w][lrow][nt * 16 + (lgrp << 2)] = pb;
    }

    // PV: A = own-wave P tile (16q x 64k), B = V^T tile (same-wave LDS
    // write->read; ldsP[w] is wave-private, ordered by lgkmcnt).
#pragma unroll
    for (int nt = 0; nt < 4; ++nt) {
#pragma unroll
      for (int ks = 0; ks < 2; ++ks) {
        bf16x8 pa = *(const bf16x8*)&ldsP[w][lrow][ks * 32 + lgrp * 8];
        bf16x8 vb = *(const bf16x8*)&ldsV[nt * 16 + lrow][ks * 32 + lgrp * 8];
        oacc[nt] = __builtin_amdgcn_mfma_f32_16x16x32_bf16(pa, vb, oacc[nt], 0, 0, 0);
      }
    }
  }

  // ---- write O (fp32): O row = q0+16w+4*lgrp+rg, col d = nt*16+lrow ----
#pragma unroll
  for (int nt = 0; nt < 4; ++nt) {
#pragma unroll
    for (int rg = 0; rg < 4; ++rg) {
      const int rl = (lgrp << 2) + rg;
      const int d  = nt * 16 + lrow;
      __builtin_nontemporal_store(
          oacc[nt][rg],
          outO + ((size_t)(bh * S_LEN + q0 + (w << 4) + rl)) * 64 + d);
    }
  }
}

extern "C" void kernel_launch(void* const* d_in, const int* in_sizes, int n_in,
                              void* d_out, int out_size, void* d_ws, size_t ws_size,
                              hipStream_t stream) {
  const float* Q = (const float*)d_in[0];
  const float* K = (const float*)d_in[1];
  const float* V = (const float*)d_in[2];
  // d_in[3] (mask) is statically causal -> not read.
  float* outO = (float*)d_out;
  float* outP = outO + (size_t)32 * S_LEN * 64;  // after [B,H,S,D] output

  const size_t need = (size_t)2 * NELEM * sizeof(short);  // 16.8 MB
  if (ws_size >= need) {
    short* Kw = (short*)d_ws;
    short* Vw = Kw + NELEM;
    transcode_kernel<<<dim3(NELEM / 8 / 256), dim3(256), 0, stream>>>(K, V, Kw, Vw);
    sdpa_kernel<true><<<dim3(32 * 32), dim3(256), 0, stream>>>(Q, Kw, Vw, outO, outP);
  } else {
    sdpa_kernel<false><<<dim3(32 * 32), dim3(256), 0, stream>>>(Q, K, V, outO, outP);
  }
}